// Round 15
// baseline (48.810 us; speedup 1.0000x reference)
//
#include <hip/hip_runtime.h>
#include <hip/hip_bf16.h>
#include <stdint.h>

// out[b,o,p] = sum_{r,c} mat0[b,c,p] * mat1[o,c,r]*Alpha[r] * mask[r,p]
// GEMM: M=256 (o), N=32768 (n=b*4096+p), K=2048 (k=c*8+r).
// A[o,k] = mat1[o,c,r]*Alpha[r]  (prepped FP16 in d_ws, layout [c][o][8r])
// B[k,n] = mat0[b,c,p]*mask[r,p] synthesized IN REGISTERS per lane (fp16).
// Round 15: 4 waves/SIMD + LDS-staged A (the untested quadrant; R6/R7's
// 4-wave attempts had no LDS and hit the VMEM wall, R9-R14's LDS versions
// had only 2 waves/SIMD and stalled on latency). 512-thread blocks, 8 waves
// = 2M x 4N, wave = 64x32 out (acc 32 VGPR, ~86 total: honest fit under the
// (512,4) cap). R14's pointer-bump + read-ahead + 4-slab ring + barrier per
// 2 rounds retained; super-top wait is counted vmcnt(8) (stage DMAs only;
// compiler inserts precise waits for P-register uses).

typedef __attribute__((ext_vector_type(8)))  _Float16 half8;
typedef __attribute__((ext_vector_type(16))) float    f32x16;

#define C_IN  256
#define HW_   4096

__global__ __launch_bounds__(256) void prep_w_kernel(
    const float* __restrict__ mat1, const float* __restrict__ Alpha,
    const int* __restrict__ use_alpha, _Float16* __restrict__ Aprep) {
  int t = blockIdx.x * 256 + threadIdx.x;   // o = t&255, c = t>>8
  int o = t & 255;
  int c = t >> 8;
  int ua = use_alpha[0];
  const float* src = mat1 + ((size_t)o * C_IN + c) * 8;
  half8 v;
#pragma unroll
  for (int r = 0; r < 8; ++r) {
    float s = ua ? Alpha[r] : 1.0f;
    v[r] = (_Float16)(src[r] * s);
  }
  // layout: slot (c*256 + o) holds 8 fp16 (r fastest)
  *(half8*)(Aprep + ((size_t)c * 256 + o) * 8) = v;
}

__global__ __launch_bounds__(512, 4) void gemm_deform_kernel(
    const float* __restrict__ mat0, const _Float16* __restrict__ Aprep,
    const float* __restrict__ mask, float* __restrict__ out) {
  // slab = one round: slot = cq*128 + (o-o0), cq 0..7, 16B slots
  __shared__ half8 A_lds[4][1024];   // 64 KiB, 4-slab ring (slab = rd%4)

  int bid = blockIdx.x;
  int wg = (bid & 7) * 64 + (bid >> 3);   // XCD swizzle (512%8==0, bijective)
  int tile_m = wg & 1;                    // M fastest: pair shares mat0 cols
  int tile_n = wg >> 1;                   // 0..255
  int o0 = tile_m * 128;
  int n0 = tile_n * 128;
  int b  = n0 >> 12;
  int p0 = n0 & 4095;

  int t    = threadIdx.x;   // 0..511
  int lane = t & 63;
  int w    = t >> 6;        // 0..7
  int wc   = w & 3;         // 4 N-groups of 32 cols
  int wr   = w >> 2;        // 2 M-groups of 64 rows
  int l31  = lane & 31;
  int cr   = lane >> 5;     // c-plane parity within MFMA K=16

  // lane-resident packed fp16 mask for this wave's single 32-col group
  int colb = p0 + wc * 32 + l31;
  half8 mkh;
#pragma unroll
  for (int r = 0; r < 8; ++r) mkh[r] = (_Float16)mask[r * HW_ + colb];

  // ---- pointer-bump state ----
  const __attribute__((address_space(1))) uint32_t* gA =
      (const __attribute__((address_space(1))) uint32_t*)Aprep;
  __attribute__((address_space(3))) uint32_t* lA =
      (__attribute__((address_space(3))) uint32_t*)&A_lds[0][0];
  int srow = t & 127;       // staged A-row within tile
  int scq  = t >> 7;        // 0..3: this thread stages c-planes scq, scq+4
  // stage pointers (dword units); +8192 dwords (one round = 32KB) per round
  const __attribute__((address_space(1))) uint32_t* gS0 =
      gA + (size_t)(scq * 256 + o0 + srow) * 4;
  const __attribute__((address_space(1))) uint32_t* gS1 =
      gA + (size_t)((4 + scq) * 256 + o0 + srow) * 4;
  // P pointers kq=0..3 (plane c = rd*8 + kq*2 + cr, column colb)
  const float* __restrict__ m0b =
      mat0 + ((size_t)b * C_IN + cr) * HW_ + colb;
  const float* pP0 = m0b + (size_t)0 * HW_;
  const float* pP1 = m0b + (size_t)2 * HW_;
  const float* pP2 = m0b + (size_t)4 * HW_;
  const float* pP3 = m0b + (size_t)6 * HW_;

  // dest slots t and t+512 are exactly (scq*128+srow) and ((4+scq)*128+srow)
#define STAGE(SLAB, SB) do {                                                  \
    __builtin_amdgcn_global_load_lds(gS0, lA + (size_t)((SLAB)*1024 + t) * 4,       16, 0, 0); \
    __builtin_amdgcn_global_load_lds(gS1, lA + (size_t)((SLAB)*1024 + 512 + t) * 4, 16, 0, 0); \
    gS0 += (SB); gS1 += (SB);                                                 \
  } while (0)

  f32x16 acc0, acc1;   // mi = 0,1 (rows wr*64 + mi*32 + ...)
#pragma unroll
  for (int j = 0; j < 16; ++j) { acc0[j] = 0.f; acc1[j] = 0.f; }

  float Pev[4], Pod[4];   // P sets for even/odd rounds

  auto SM = [&](float s, half8 A0, half8 A1) {
    _Float16 h = (_Float16)s;
    half8 pb = {h, h, h, h, h, h, h, h};
    half8 bv = pb * mkh;   // 4x v_pk_mul_f16
    acc0 = __builtin_amdgcn_mfma_f32_32x32x16_f16(A0, bv, acc0, 0, 0, 0);
    acc1 = __builtin_amdgcn_mfma_f32_32x32x16_f16(A1, bv, acc1, 0, 0, 0);
  };

  int abase = wr * 64 + l31;   // + (kq*2+cr)*128, +32 for mi=1

  // COMP one round from slab Ab; read-ahead next kq's frags; refill P (+PB)
  auto COMP = [&](const half8* __restrict__ Ab, float (&P)[4], int PB) {
    half8 a0 = Ab[(0 + cr) * 128 + abase];
    half8 a1 = Ab[(0 + cr) * 128 + abase + 32];
    half8 b0 = Ab[(2 + cr) * 128 + abase];
    half8 b1 = Ab[(2 + cr) * 128 + abase + 32];
    SM(P[0], a0, a1);
    P[0] = pP0[0]; pP0 += PB;
    a0 = Ab[(4 + cr) * 128 + abase];
    a1 = Ab[(4 + cr) * 128 + abase + 32];
    SM(P[1], b0, b1);
    P[1] = pP1[0]; pP1 += PB;
    b0 = Ab[(6 + cr) * 128 + abase];
    b1 = Ab[(6 + cr) * 128 + abase + 32];
    SM(P[2], a0, a1);
    P[2] = pP2[0]; pP2 += PB;
    SM(P[3], b0, b1);
    P[3] = pP3[0]; pP3 += PB;
  };

  // ---- prologue: stage rounds 0,1 (slabs 0,1); load P rounds 0,1 ----
  STAGE(0, 8192);
  STAGE(1, 8192);
  Pev[0] = pP0[0]; pP0 += 8 * HW_;
  Pev[1] = pP1[0]; pP1 += 8 * HW_;
  Pev[2] = pP2[0]; pP2 += 8 * HW_;
  Pev[3] = pP3[0]; pP3 += 8 * HW_;
  Pod[0] = pP0[0]; pP0 += 8 * HW_;
  Pod[1] = pP1[0]; pP1 += 8 * HW_;
  Pod[2] = pP2[0]; pP2 += 8 * HW_;
  Pod[3] = pP3[0]; pP3 += 8 * HW_;
  // stage + P pointers now at round 2

  // ---- main loop: 4 rounds/iter; counted vmcnt(8) + barrier every 2 ----
#pragma unroll 1
  for (int g = 0; g < 8; ++g) {
    int rd = g * 4;
    // rounds rd, rd+1 (slabs 0,1); stage rd+2, rd+3 (slabs 2,3)
    asm volatile("s_waitcnt vmcnt(8)" ::: "memory");   // drain stage DMAs only
    __builtin_amdgcn_s_barrier();                      // all waves past rd-1
    {
      int sb2 = (rd + 2 < 31) ? 8192 : 0;
      int sb3 = (rd + 3 < 31) ? 8192 : 0;
      int pb2 = (rd + 2 < 31) ? 8 * HW_ : 0;
      int pb3 = (rd + 3 < 31) ? 8 * HW_ : 0;
      STAGE(2, sb2);
      STAGE(3, sb3);
      COMP(&A_lds[0][0], Pev, pb2);
      COMP(&A_lds[1][0], Pod, pb3);
    }
    // rounds rd+2, rd+3 (slabs 2,3); stage rd+4, rd+5 (slabs 0,1)
    asm volatile("s_waitcnt vmcnt(8)" ::: "memory");
    __builtin_amdgcn_s_barrier();
    {
      int sb4 = (rd + 4 < 31) ? 8192 : 0;
      int sb5 = (rd + 5 < 31) ? 8192 : 0;
      int pb4 = (rd + 4 < 31) ? 8 * HW_ : 0;
      int pb5 = (rd + 5 < 31) ? 8 * HW_ : 0;
      STAGE(0, sb4);
      STAGE(1, sb5);
      COMP(&A_lds[2][0], Pev, pb4);
      COMP(&A_lds[3][0], Pod, pb5);
    }
  }

  // ---- epilogue: 32x32 C/D layout col=lane&31, row=(reg&3)+8*(reg>>2)+4*cr ----
  size_t obase = (size_t)b * 256 * HW_ + colb;
#pragma unroll
  for (int reg = 0; reg < 16; ++reg) {
    int row = o0 + wr * 64 + (reg & 3) + 8 * (reg >> 2) + 4 * cr;
    out[obase + (size_t)row * HW_]        = acc0[reg];
    out[obase + (size_t)(row + 32) * HW_] = acc1[reg];
  }
}

extern "C" void kernel_launch(void* const* d_in, const int* in_sizes, int n_in,
                              void* d_out, int out_size, void* d_ws, size_t ws_size,
                              hipStream_t stream) {
  const float* mat0      = (const float*)d_in[0];   // [8,256,64,64]
  const float* mat1      = (const float*)d_in[1];   // [256,256,8]
  const float* mask      = (const float*)d_in[2];   // [8,64,64]
  const float* Alpha     = (const float*)d_in[3];   // [8]
  const int*   use_alpha = (const int*)d_in[4];     // [1]
  (void)in_sizes; (void)n_in; (void)out_size; (void)ws_size;

  _Float16* Aprep = (_Float16*)d_ws;                // 1 MiB scratch
  float* outp  = (float*)d_out;

  prep_w_kernel<<<256, 256, 0, stream>>>(mat1, Alpha, use_alpha, Aprep);
  gemm_deform_kernel<<<512, 512, 0, stream>>>(mat0, Aprep, mask, outp);
}